// Round 4
// baseline (508.420 us; speedup 1.0000x reference)
//
#include <hip/hip_runtime.h>
#include <cstddef>
#include <cstdint>

// LinearAttention — bf16 MFMA, global_load_lds staging, XOR-swizzled LDS.
// B=4 L=4096 D=1024 H=16 d=64 M=128 (2M=256).
// Pipeline: convert x+weights -> K1 fused QKV GEMM (q,k natural; v transposed)
// -> K2 fourier(k)+kv outer -> split-K fp32 partials (no atomics)
// -> K2.5 reduce 8 partials + transpose -> kvT bf16
// -> K3 fourier(q)+attn -> K4 out GEMM.
//
// ws layout (bytes):
//   qb     @ 0          33.55MB  bf16 [16384][1024]
//   kb     @ 33554432   33.55MB  bf16 [16384][1024]   (reused as attnb)
//   vT     @ 67108864   33.55MB  bf16 [(b*16+h)*64+d][4096]  (reused as kvT)
//   xb     @ 100663296  33.55MB  bf16 [16384][1024]   (parts f32 32MB overlays after K1)
//   Wqkvb  @ 134217728   6.29MB  bf16 [3072][1024]
//   Wob    @ 140509184   2.10MB  bf16 [1024][1024]
//   projT  @ 142606336   16KB    bf16 [128 m][64 d]
// total ~136MB.

typedef __attribute__((ext_vector_type(8))) short s8v;   // 8 x bf16 (16B)
typedef __attribute__((ext_vector_type(4))) short s4v;   // 4 x bf16 (8B)
typedef __attribute__((ext_vector_type(4))) float f32x4; // MFMA acc

#define MFMA_BF16(a, b, c) __builtin_amdgcn_mfma_f32_16x16x32_bf16((a), (b), (c), 0, 0, 0)

#define P_SCALE 0.125f                 // 1/sqrt(64)
#define F_SCALE 0.08838834764831845f   // 1/sqrt(128)

static __device__ __forceinline__ unsigned short f2bf(float f) {
  unsigned int u = __float_as_uint(f);
  u += 0x7fffu + ((u >> 16) & 1u);  // RNE
  return (unsigned short)(u >> 16);
}

// async 16B global->LDS (DMA; LDS dest = wave-uniform base + lane*16)
static __device__ __forceinline__ void gload_lds16(const void* g, void* l) {
  __builtin_amdgcn_global_load_lds(
      (const __attribute__((address_space(1))) unsigned int*)g,
      (__attribute__((address_space(3))) unsigned int*)l, 16, 0, 0);
}

// ---------------------------------------------------------------------------
// K0a: fp32 -> bf16 elementwise convert
// ---------------------------------------------------------------------------
__global__ void conv_bf16_kernel(const float* __restrict__ src, short* __restrict__ dst, int n) {
  int i4 = (blockIdx.x * 256 + threadIdx.x) * 4;
  if (i4 < n) {
    float4 f = *(const float4*)(src + i4);
    s4v v;
    v[0] = (short)f2bf(f.x); v[1] = (short)f2bf(f.y);
    v[2] = (short)f2bf(f.z); v[3] = (short)f2bf(f.w);
    *(s4v*)(dst + i4) = v;
  }
}

// K0b: proj [64][128] f32 -> projT [128][64] bf16
__global__ void projT_kernel(const float* __restrict__ proj, short* __restrict__ projT) {
  int t = threadIdx.x;
#pragma unroll
  for (int i = 0; i < 32; ++i) {
    int idx = t + i * 256;
    int d = idx >> 7, m = idx & 127;
    projT[m * 64 + d] = (short)f2bf(proj[idx]);
  }
}

// ---------------------------------------------------------------------------
// K1: qkv = xb @ Wqkv^T + bias. 128x128 tile, BK=64, bf16 MFMA,
// global_load_lds staging with XOR chunk swizzle.
// grid (128 row-tiles, 24 col-tiles). bn 0-7: q, 8-15: k, 16-23: v.
// ---------------------------------------------------------------------------
__global__ void qkv_gemm_kernel(const short* __restrict__ xb,
                                const short* __restrict__ Wqkv,
                                const float* __restrict__ bq_, const float* __restrict__ bk_,
                                const float* __restrict__ bv_,
                                short* __restrict__ qb, short* __restrict__ kb,
                                short* __restrict__ vT) {
  __shared__ __align__(16) short smem[17408];  // A[128][64]+B[128][64]; epi image [128][136]
  short* Al = smem;
  short* Bl = smem + 8192;

  const int t = threadIdx.x;
  const int bm = blockIdx.x, bn = blockIdx.y;
  const int row0 = bm * 128, n0 = bn * 128;
  const int lane = t & 63, w = t >> 6;
  const int wm = w & 1, wn = w >> 1;
  const int l15 = lane & 15, lq = lane >> 4;
  const int sx = (l15 & 7) * 8;   // fragment-read swizzle term (in shorts)

  f32x4 acc[4][4];
#pragma unroll
  for (int i = 0; i < 4; ++i)
#pragma unroll
    for (int j = 0; j < 4; ++j) acc[i][j] = (f32x4){0.f, 0.f, 0.f, 0.f};

  for (int k0 = 0; k0 < 1024; k0 += 64) {
#pragma unroll
    for (int i = 0; i < 4; ++i) {
      int c = t + i * 256;                 // chunk 0..1023
      int r = c >> 3, cl = c & 7;
      int cg = cl ^ (r & 7);               // permuted global chunk
      gload_lds16(xb   + (size_t)(row0 + r) * 1024 + k0 + cg * 8, Al + c * 8);
      gload_lds16(Wqkv + (size_t)(n0 + r) * 1024 + k0 + cg * 8, Bl + c * 8);
    }
    __syncthreads();
#pragma unroll
    for (int ks = 0; ks < 2; ++ks) {
      const int kb8 = (ks * 4 + lq) * 8;
      s8v af[4], bfr[4];
#pragma unroll
      for (int i = 0; i < 4; ++i)
        af[i] = *(s8v*)&Al[(wm * 64 + i * 16 + l15) * 64 + (kb8 ^ sx)];
#pragma unroll
      for (int j = 0; j < 4; ++j)
        bfr[j] = *(s8v*)&Bl[(wn * 64 + j * 16 + l15) * 64 + (kb8 ^ sx)];
#pragma unroll
      for (int i = 0; i < 4; ++i)
#pragma unroll
        for (int j = 0; j < 4; ++j)
          acc[i][j] = MFMA_BF16(af[i], bfr[j], acc[i][j]);
    }
    __syncthreads();
  }

  const int region = bn >> 3;  // 0 q, 1 k, 2 v
  if (region < 2) {
    const float* bias = (region == 0) ? bq_ : bk_;
    short* IM = smem;  // [128][136] natural image
#pragma unroll
    for (int j = 0; j < 4; ++j) {
      int cl = wn * 64 + j * 16 + l15;
      float bsv = bias[(n0 & 1023) + cl];
#pragma unroll
      for (int i = 0; i < 4; ++i)
#pragma unroll
        for (int r = 0; r < 4; ++r)
          IM[(wm * 64 + i * 16 + lq * 4 + r) * 136 + cl] = (short)f2bf(acc[i][j][r] + bsv);
    }
    __syncthreads();
    short* dst = (region == 0) ? qb : kb;
#pragma unroll
    for (int i = 0; i < 8; ++i) {
      int c = t + i * 256;
      int r = c >> 4, cc = c & 15;
      *(s8v*)&dst[(size_t)(row0 + r) * 1024 + (n0 & 1023) + cc * 8] =
          *(s8v*)&IM[r * 136 + cc * 8];
    }
  } else {
    short* IM = smem;  // [128 col][136] transposed image
#pragma unroll
    for (int j = 0; j < 4; ++j) {
      int cl = wn * 64 + j * 16 + l15;
      float bsv = bv_[(n0 - 2048) + cl];
#pragma unroll
      for (int i = 0; i < 4; ++i) {
        s4v pk;
#pragma unroll
        for (int r = 0; r < 4; ++r) pk[r] = (short)f2bf(acc[i][j][r] + bsv);
        *(s4v*)&IM[cl * 136 + wm * 64 + i * 16 + lq * 4] = pk;
      }
    }
    __syncthreads();
    const int b = row0 >> 12;
    const int l0 = (bm & 31) * 128;
#pragma unroll
    for (int i = 0; i < 8; ++i) {
      int c = t + i * 256;
      int ci = c >> 4, cc = c & 15;
      int cv = (bn - 16) * 128 + ci;      // 0..1023
      int grow = (b * 16 + (cv >> 6)) * 64 + (cv & 63);
      *(s8v*)&vT[(size_t)grow * 4096 + l0 + cc * 8] = *(s8v*)&IM[ci * 136 + cc * 8];
    }
  }
}

// ---------------------------------------------------------------------------
// K2: per (b,h,512-row chunk): fourier(k) -> k' ; kv += k'^T @ v  (MFMA).
// Split-K partials (no atomics): parts[bid][256 m][64 d] f32, plain stores.
// Wave-private k' LDS region -> only ONE barrier per 64-row stage.
// kt double-buffered (prefetch a full stage ahead); vt hidden under fourier.
// grid 512.
// ---------------------------------------------------------------------------
__global__ void kv_accum_kernel(const short* __restrict__ kb, const short* __restrict__ vT,
                                const short* __restrict__ projT, float* __restrict__ parts) {
  __shared__ __align__(16) short smem[28672];  // kt0|kt1|vt|kpT(4 waves x 4096) = 57.3KB
  short* const ktb0 = smem;
  short* const ktb1 = smem + 4096;
  short* const vt   = smem + 8192;
  short* const kpT  = smem + 12288;

  const int t = threadIdx.x;
  const int bid = blockIdx.x;
  const int chunk = bid & 7, h = (bid >> 3) & 15, b = bid >> 7;
  const int lane = t & 63, w = t >> 6;
  const int l15 = lane & 15, lq = lane >> 4;
  const int sx = (l15 & 7) * 8;
  const int g = w & 1;        // nt-group: m' 0..63 or 64..127
  const int trig = w >> 1;    // 0 = cos (m 0..127), 1 = sin (m 128..255)

  // staging decomposition (per thread, 2 chunks)
  const int c0 = t, c1 = t + 256;
  const int r0 = c0 >> 3, cg0 = (c0 & 7) ^ (r0 & 7);
  const int r1 = c1 >> 3, cg1 = (c1 & 7) ^ (r1 & 7);

  const short* kbase = kb + (size_t)(b * 4096 + chunk * 512) * 1024 + h * 64;
  const short* vbase = vT + ((size_t)((b * 16 + h) * 64)) * 4096 + chunk * 512;

  // B-fragments of projT for this wave's 4 m'-tiles
  s8v pf[4][2];
#pragma unroll
  for (int ntl = 0; ntl < 4; ++ntl)
#pragma unroll
    for (int ks = 0; ks < 2; ++ks)
      pf[ntl][ks] = *(const s8v*)(projT + (size_t)((g * 4 + ntl) * 16 + l15) * 64 + ks * 32 + lq * 8);

  f32x4 kvacc[4][4];
#pragma unroll
  for (int i = 0; i < 4; ++i)
#pragma unroll
    for (int j = 0; j < 4; ++j) kvacc[i][j] = (f32x4){0.f, 0.f, 0.f, 0.f};

  // prefetch kt(0)
  gload_lds16(kbase + (size_t)r0 * 1024 + cg0 * 8, ktb0 + c0 * 8);
  gload_lds16(kbase + (size_t)r1 * 1024 + cg1 * 8, ktb0 + c1 * 8);

  for (int s = 0; s < 8; ++s) {
    __syncthreads();  // drains vmcnt(0): kt(s) ready; all waves done with prev buffers

    // issue vt(s) then kt(s+1) — 4 outstanding DMA per wave
    gload_lds16(vbase + (size_t)r0 * 4096 + s * 64 + cg0 * 8, vt + c0 * 8);
    gload_lds16(vbase + (size_t)r1 * 4096 + s * 64 + cg1 * 8, vt + c1 * 8);
    const int sp = (s < 7) ? s + 1 : 7;   // dummy reload on last stage keeps vmcnt math fixed
    short* ktn = ((s + 1) & 1) ? ktb1 : ktb0;
    gload_lds16(kbase + (size_t)(sp * 64 + r0) * 1024 + cg0 * 8, ktn + c0 * 8);
    gload_lds16(kbase + (size_t)(sp * 64 + r1) * 1024 + cg1 * 8, ktn + c1 * 8);

    const short* kt = (s & 1) ? ktb1 : ktb0;

    // fourier: this wave computes p[all 64 rows][its 64 m'] = k_tile @ projT
    f32x4 pacc[4][4];  // [rt][ntl]
#pragma unroll
    for (int rt = 0; rt < 4; ++rt)
#pragma unroll
      for (int ntl = 0; ntl < 4; ++ntl) pacc[rt][ntl] = (f32x4){0.f, 0.f, 0.f, 0.f};
#pragma unroll
    for (int ks = 0; ks < 2; ++ks) {
      const int kb8 = (ks * 4 + lq) * 8;
      s8v af[4];
#pragma unroll
      for (int rt = 0; rt < 4; ++rt)
        af[rt] = *(const s8v*)&kt[(rt * 16 + l15) * 64 + (kb8 ^ sx)];
#pragma unroll
      for (int rt = 0; rt < 4; ++rt)
#pragma unroll
        for (int ntl = 0; ntl < 4; ++ntl)
          pacc[rt][ntl] = MFMA_BF16(af[rt], pf[ntl][ks], pacc[rt][ntl]);
    }

    // sincos -> wave-private k'T[m_local][row], XOR-swizzled row-chunks
    short* kp = kpT + w * 4096;
#pragma unroll
    for (int rt = 0; rt < 4; ++rt)
#pragma unroll
      for (int ntl = 0; ntl < 4; ++ntl) {
        s4v pk;
#pragma unroll
        for (int r = 0; r < 4; ++r) {
          float p = pacc[rt][ntl][r] * P_SCALE;
          float fv = trig ? __sinf(p) : __cosf(p);
          pk[r] = (short)f2bf(fv * F_SCALE);
        }
        int m = ntl * 16 + l15;
        int rowc = rt * 2 + (lq >> 1);
        *(s4v*)&kp[m * 64 + (((rowc ^ (m & 7)) << 3) | ((lq & 1) << 2))] = pk;
      }

    // vt(s) ready once <=2 loads outstanding (the 2 kt(s+1) may still fly)
    asm volatile("s_waitcnt vmcnt(2)" ::: "memory");

    // kv MFMA: D[m_local][d] over this stage's 64 rows (K), wave-private A
#pragma unroll
    for (int ks = 0; ks < 2; ++ks) {
      const int kb8 = (ks * 4 + lq) * 8;
      s8v akv[4], bkv[4];
#pragma unroll
      for (int i = 0; i < 4; ++i)
        akv[i] = *(const s8v*)&kp[(i * 16 + l15) * 64 + (kb8 ^ sx)];
#pragma unroll
      for (int j = 0; j < 4; ++j)
        bkv[j] = *(const s8v*)&vt[(j * 16 + l15) * 64 + (kb8 ^ sx)];
#pragma unroll
      for (int i = 0; i < 4; ++i)
#pragma unroll
        for (int j = 0; j < 4; ++j)
          kvacc[i][j] = MFMA_BF16(akv[i], bkv[j], kvacc[i][j]);
    }
  }

  // flush fp32 partials, plain coalesced stores
  float* pb = parts + ((size_t)bid << 14);
#pragma unroll
  for (int i = 0; i < 4; ++i)
#pragma unroll
    for (int j = 0; j < 4; ++j)
#pragma unroll
      for (int r = 0; r < 4; ++r) {
        int m = w * 64 + i * 16 + lq * 4 + r;
        int d = j * 16 + l15;
        pb[(size_t)m * 64 + d] = kvacc[i][j][r];
      }
}

// ---------------------------------------------------------------------------
// K2.5: kvT[bh*64+d][256 m] bf16 = transpose(sum over 8 chunks of parts).
// grid 64.
// ---------------------------------------------------------------------------
__global__ void kv_reduce_kernel(const float* __restrict__ parts, short* __restrict__ kvT) {
  __shared__ short im[16896];  // [64 d][264]
  const int t = threadIdx.x;
  const int bh = blockIdx.x;
  const float* p0 = parts + ((size_t)bh << 17);  // bh*8*16384
#pragma unroll 4
  for (int i = 0; i < 64; ++i) {
    int idx = t + i * 256;
    float s = 0.f;
#pragma unroll
    for (int c = 0; c < 8; ++c) s += p0[(c << 14) + idx];
    im[(idx & 63) * 264 + (idx >> 6)] = (short)f2bf(s);
  }
  __syncthreads();
#pragma unroll
  for (int i = 0; i < 8; ++i) {
    int c = t + i * 256;
    int d = c >> 5, cc = c & 31;
    *(s8v*)&kvT[(size_t)(bh * 64 + d) * 256 + cc * 8] = *(s8v*)&im[d * 264 + cc * 8];
  }
}

// ---------------------------------------------------------------------------
// K3: fourier(q) + attn = q' @ kv, per (64-row tile, head). grid (256,16).
// ---------------------------------------------------------------------------
__global__ void attn_kernel(const short* __restrict__ qb, const short* __restrict__ projT,
                            const short* __restrict__ kvT, short* __restrict__ attnb) {
  __shared__ __align__(16) short smem[20992];  // qt[64][64]+qA[64][136]+kvt[64][128]
  short* qt = smem;
  short* qA = smem + 4096;
  short* kvt = smem + 12800;

  const int t = threadIdx.x;
  const int rt = blockIdx.x, h = blockIdx.y;
  const int row0 = rt * 64;
  const int b = row0 >> 12;
  const int lane = t & 63, w = t >> 6;
  const int l15 = lane & 15, lq = lane >> 4;
  const int sx = (l15 & 7) * 8;

  s8v pf[8][2];
#pragma unroll
  for (int nt = 0; nt < 8; ++nt)
#pragma unroll
    for (int ks = 0; ks < 2; ++ks)
      pf[nt][ks] = *(const s8v*)(projT + (size_t)(nt * 16 + l15) * 64 + ks * 32 + lq * 8);

#pragma unroll
  for (int i = 0; i < 2; ++i) {
    int c = t + i * 256;
    int r = c >> 3, cl = c & 7;
    int cg = cl ^ (r & 7);
    gload_lds16(qb + (size_t)(row0 + r) * 1024 + h * 64 + cg * 8, qt + c * 8);
  }
  __syncthreads();

  f32x4 pacc[8];
#pragma unroll
  for (int nt = 0; nt < 8; ++nt) pacc[nt] = (f32x4){0.f, 0.f, 0.f, 0.f};
#pragma unroll
  for (int ks = 0; ks < 2; ++ks) {
    const int kb8 = (ks * 4 + lq) * 8;
    s8v af = *(s8v*)&qt[(w * 16 + l15) * 64 + (kb8 ^ sx)];
#pragma unroll
    for (int nt = 0; nt < 8; ++nt) pacc[nt] = MFMA_BF16(af, pf[nt][ks], pacc[nt]);
  }

  f32x4 aacc[4];
#pragma unroll
  for (int j = 0; j < 4; ++j) aacc[j] = (f32x4){0.f, 0.f, 0.f, 0.f};

#pragma unroll
  for (int half = 0; half < 2; ++half) {
    // q' half -> qA [64][136]
#pragma unroll
    for (int nt = 0; nt < 8; ++nt)
#pragma unroll
      for (int r = 0; r < 4; ++r) {
        float p = pacc[nt][r] * P_SCALE;
        float fv = (half == 0) ? __cosf(p) : __sinf(p);
        qA[(w * 16 + lq * 4 + r) * 136 + nt * 16 + l15] = (short)f2bf(fv * F_SCALE);
      }
    // stage kvT half: [64 d][128 m'], swizzled (16 chunks/row)
#pragma unroll
    for (int i = 0; i < 4; ++i) {
      int c = t + i * 256;                 // chunk 0..1023
      int d = c >> 4, cl = c & 15;
      int cg = cl ^ (d & 15);
      gload_lds16(kvT + (size_t)((b * 16 + h) * 64 + d) * 256 + half * 128 + cg * 8,
                  kvt + c * 8);
    }
    __syncthreads();
#pragma unroll
    for (int ks = 0; ks < 4; ++ks) {
      s8v af = *(s8v*)&qA[(w * 16 + l15) * 136 + ks * 32 + lq * 8];
#pragma unroll
      for (int j = 0; j < 4; ++j) {
        int row = j * 16 + l15;
        s8v bf4 = *(s8v*)&kvt[row * 128 + (((ks * 4 + lq) ^ l15) * 8)];
        aacc[j] = MFMA_BF16(af, bf4, aacc[j]);
      }
    }
    __syncthreads();
  }

  // epilogue image at smem base [64][72]
#pragma unroll
  for (int j = 0; j < 4; ++j)
#pragma unroll
    for (int r = 0; r < 4; ++r)
      smem[(w * 16 + lq * 4 + r) * 72 + j * 16 + l15] = (short)f2bf(aacc[j][r]);
  __syncthreads();
#pragma unroll
  for (int i = 0; i < 2; ++i) {
    int c = t + i * 256;
    int r = c >> 3, cc = c & 7;
    *(s8v*)&attnb[(size_t)(row0 + r) * 1024 + h * 64 + cc * 8] = *(s8v*)&smem[r * 72 + cc * 8];
  }
}

// ---------------------------------------------------------------------------
// K4: out = attn @ Wo^T + bo. fp32 out. grid (128, 8).
// ---------------------------------------------------------------------------
__global__ void out_gemm_kernel(const short* __restrict__ attnb, const short* __restrict__ Wob,
                                const float* __restrict__ bo_, float* __restrict__ out) {
  __shared__ __align__(16) short smem[16384];
  short* Al = smem;
  short* Bl = smem + 8192;

  const int t = threadIdx.x;
  const int bm = blockIdx.x, bn = blockIdx.y;
  const int row0 = bm * 128, n0 = bn * 128;
  const int lane = t & 63, w = t >> 6;
  const int wm = w & 1, wn = w >> 1;
  const int l15 = lane & 15, lq = lane >> 4;
  const int sx = (l15 & 7) * 8;

  f32x4 acc[4][4];
#pragma unroll
  for (int i = 0; i < 4; ++i)
#pragma unroll
    for (int j = 0; j < 4; ++j) acc[i][j] = (f32x4){0.f, 0.f, 0.f, 0.f};

  for (int k0 = 0; k0 < 1024; k0 += 64) {
#pragma unroll
    for (int i = 0; i < 4; ++i) {
      int c = t + i * 256;
      int r = c >> 3, cl = c & 7;
      int cg = cl ^ (r & 7);
      gload_lds16(attnb + (size_t)(row0 + r) * 1024 + k0 + cg * 8, Al + c * 8);
      gload_lds16(Wob   + (size_t)(n0 + r) * 1024 + k0 + cg * 8, Bl + c * 8);
    }
    __syncthreads();
#pragma unroll
    for (int ks = 0; ks < 2; ++ks) {
      const int kb8 = (ks * 4 + lq) * 8;
      s8v af[4], bfr[4];
#pragma unroll
      for (int i = 0; i < 4; ++i)
        af[i] = *(s8v*)&Al[(wm * 64 + i * 16 + l15) * 64 + (kb8 ^ sx)];
#pragma unroll
      for (int j = 0; j < 4; ++j)
        bfr[j] = *(s8v*)&Bl[(wn * 64 + j * 16 + l15) * 64 + (kb8 ^ sx)];
#pragma unroll
      for (int i = 0; i < 4; ++i)
#pragma unroll
        for (int j = 0; j < 4; ++j)
          acc[i][j] = MFMA_BF16(af[i], bfr[j], acc[i][j]);
    }
    __syncthreads();
  }

#pragma unroll
  for (int j = 0; j < 4; ++j) {
    int cl = wn * 64 + j * 16 + l15;
    float bsv = bo_[n0 + cl];
#pragma unroll
    for (int i = 0; i < 4; ++i)
#pragma unroll
      for (int r = 0; r < 4; ++r)
        out[(size_t)(row0 + wm * 64 + i * 16 + lq * 4 + r) * 1024 + n0 + cl] =
            acc[i][j][r] + bsv;
  }
}

// ---------------------------------------------------------------------------
extern "C" void kernel_launch(void* const* d_in, const int* in_sizes, int n_in,
                              void* d_out, int out_size, void* d_ws, size_t ws_size,
                              hipStream_t stream) {
  const float* x    = (const float*)d_in[0];
  const float* proj = (const float*)d_in[1];
  const float* Wq   = (const float*)d_in[2];
  const float* bq   = (const float*)d_in[3];
  const float* Wk   = (const float*)d_in[4];
  const float* bk   = (const float*)d_in[5];
  const float* Wv   = (const float*)d_in[6];
  const float* bv   = (const float*)d_in[7];
  const float* Wo   = (const float*)d_in[8];
  const float* bo   = (const float*)d_in[9];
  float* out = (float*)d_out;

  char* wsb = (char*)d_ws;
  short* qb    = (short*)(wsb + 0);
  short* kb    = (short*)(wsb + 33554432);
  short* vT    = (short*)(wsb + 67108864);
  short* xb    = (short*)(wsb + 100663296);
  short* Wqkvb = (short*)(wsb + 134217728);
  short* Wob   = (short*)(wsb + 140509184);
  short* projT = (short*)(wsb + 142606336);
  float* parts = (float*)(wsb + 100663296);  // overlays xb (dead after K1), 32MB
  short* attnb = kb;                          // kb dead after K2
  short* kvT   = vT;                          // vT dead after K2

  const int WN = 1024 * 1024;
  conv_bf16_kernel<<<dim3(16384), dim3(256), 0, stream>>>(x, xb, 16777216);
  conv_bf16_kernel<<<dim3(WN / 1024), dim3(256), 0, stream>>>(Wq, Wqkvb, WN);
  conv_bf16_kernel<<<dim3(WN / 1024), dim3(256), 0, stream>>>(Wk, Wqkvb + WN, WN);
  conv_bf16_kernel<<<dim3(WN / 1024), dim3(256), 0, stream>>>(Wv, Wqkvb + 2 * WN, WN);
  conv_bf16_kernel<<<dim3(WN / 1024), dim3(256), 0, stream>>>(Wo, Wob, WN);
  projT_kernel<<<dim3(1), dim3(256), 0, stream>>>(proj, projT);

  qkv_gemm_kernel<<<dim3(128, 24), dim3(256), 0, stream>>>(xb, Wqkvb, bq, bk, bv, qb, kb, vT);
  kv_accum_kernel<<<dim3(512), dim3(256), 0, stream>>>(kb, vT, projT, parts);
  kv_reduce_kernel<<<dim3(64), dim3(256), 0, stream>>>(parts, kvT);
  attn_kernel<<<dim3(256, 16), dim3(256), 0, stream>>>(qb, projT, kvT, attnb);
  out_gemm_kernel<<<dim3(128, 8), dim3(256), 0, stream>>>(attnb, Wob, bo, out);
}